// Round 11
// baseline (325.653 us; speedup 1.0000x reference)
//
#include <hip/hip_runtime.h>
#include <math.h>

// Qwen2 block: B=8 L=16 E=2048 S0=4096 F=5632 H=16 HKV=2 D=128
#define MM 128
#define EE 2048
#define FF 5632
#define S0C 4096
#define STOT 4112
#define NSPLIT 32
#define LDQKV 2560

typedef float f32x4 __attribute__((ext_vector_type(4)));
typedef short s16x8 __attribute__((ext_vector_type(8)));

#define MFMA16(a, b, c) __builtin_amdgcn_mfma_f32_16x16x32_bf16(a, b, c, 0, 0, 0)

// round-half-up fp32->bf16 (1 VALU); pack two via v_perm (3 VALU / 2 elems)
__device__ __forceinline__ unsigned short f2bfu(float f) {
    return (unsigned short)((__float_as_uint(f) + 0x8000u) >> 16);
}
__device__ __forceinline__ unsigned pk2(float lo, float hi) {
    return __builtin_amdgcn_perm(__float_as_uint(hi) + 0x8000u,
                                 __float_as_uint(lo) + 0x8000u, 0x07060302u);
}
__device__ __forceinline__ float bf2f(unsigned short u) {
    return __uint_as_float(((unsigned)u) << 16);
}

// async global->LDS DMA: 16B/lane, dest = wave-uniform base + lane*16
__device__ __forceinline__ void gload_lds(const void* g, void* l) {
    __builtin_amdgcn_global_load_lds(
        (const __attribute__((address_space(1))) void*)g,
        (__attribute__((address_space(3))) void*)l, 16, 0, 0);
}

// A-fragment layout: element (row, k) of A[128][K] lives at
//   (k>>5)*4096 + ((k>>3)&3)*1024 + row*8 + (k&7)    (shorts)
// so each 32-k step is one contiguous 8KB block; frag reads from it are dense.

// ---------------- RMSNorm -> bf16 fragged A ----------------
__global__ __launch_bounds__(256) void rmsnorm_bf16(const float* __restrict__ x,
                                                    const float* __restrict__ w,
                                                    unsigned short* __restrict__ out) {
    int row = blockIdx.x;
    int t = threadIdx.x;
    const float4* xr = (const float4*)(x + row * EE);
    float4 a = xr[2 * t];
    float4 b = xr[2 * t + 1];
    float ss = a.x*a.x + a.y*a.y + a.z*a.z + a.w*a.w
             + b.x*b.x + b.y*b.y + b.z*b.z + b.w*b.w;
    #pragma unroll
    for (int o = 32; o > 0; o >>= 1) ss += __shfl_down(ss, o);
    __shared__ float red[4];
    if ((t & 63) == 0) red[t >> 6] = ss;
    __syncthreads();
    float tot = red[0] + red[1] + red[2] + red[3];
    float inv = rsqrtf(tot * (1.0f / (float)EE) + 1e-6f);
    const float4* wr = (const float4*)w;
    float4 w0 = wr[2 * t], w1 = wr[2 * t + 1];
    float4 o0, o1;
    o0.x = a.x*inv*w0.x; o0.y = a.y*inv*w0.y; o0.z = a.z*inv*w0.z; o0.w = a.w*inv*w0.w;
    o1.x = b.x*inv*w1.x; o1.y = b.y*inv*w1.y; o1.z = b.z*inv*w1.z; o1.w = b.w*inv*w1.w;
    unsigned short* dst = out + (t >> 2) * 4096 + (t & 3) * 1024 + row * 8;
    *(uint4*)dst = make_uint4(pk2(o0.x, o0.y), pk2(o0.z, o0.w),
                              pk2(o1.x, o1.y), pk2(o1.z, o1.w));
}

// ---------------- streaming GEMM v9: 32-k ring, 4 blocks/CU ----------------
// Block = 128 rows x 64 cols, 256 threads (4 waves x 128r x 16c).
// Depth-2 LDS ring with 32-k steps: A 8KB bf16 (linear DMA) + W 8KB fp32
// (DMA with source-pre-swizzled 16B units; 128B W rows, XOR involution on
// unit index -> <=2-way LDS conflicts = free). 32KB LDS -> 4 blocks/CU.
// Loop: issue step ks+1 (4 gloads/wave) -> s_waitcnt vmcnt(4) (own step
// landed; NEVER 0 mid-loop) -> barrier -> 8 MFMA -> barrier.
// Kc % 32 == 0; last y-split may be short. P[sk][128][N] fp32 partials.
__global__ __launch_bounds__(256) void gemm_cs(const unsigned short* __restrict__ Af,
                                               const float* __restrict__ W0,
                                               const float* __restrict__ W1,
                                               const float* __restrict__ W2,
                                               int cut1, int cut2,
                                               int K, int Kc,
                                               float* __restrict__ P, int N) {
    __shared__ __align__(16) char smem[32768];   // A: 2x8KB @0, W: 2x8KB @16384
    int t = threadIdx.x;
    int wv = t >> 6, lane = t & 63, quad = lane >> 4, l15 = lane & 15;
    int nb = blockIdx.x * 64;
    const float* Wm; int nn;
    if (nb < cut1)      { Wm = W0; nn = nb; }
    else if (nb < cut2) { Wm = W1; nn = nb - cut1; }
    else                { Wm = W2; nn = nb - cut2; }
    int kbeg = blockIdx.y * Kc;
    const float* Wbase = Wm + (size_t)nn * K + kbeg;
    const unsigned short* Ab = Af + (kbeg >> 5) * 4096;
    int nk = min(Kc, K - kbeg) >> 5;

#define ISSUE(st, sl)                                                              \
    {                                                                              \
        const char* Asrc = (const char*)Ab + (size_t)(st) * 8192 + wv * 2048       \
                           + lane * 16;                                            \
        char* Adst = smem + (sl) * 8192 + wv * 2048;                               \
        gload_lds(Asrc, Adst);                                                     \
        gload_lds(Asrc + 1024, Adst + 1024);                                       \
        _Pragma("unroll")                                                          \
        for (int i = 0; i < 2; i++) {                                              \
            int wrow = wv * 16 + i * 8 + (lane >> 3);                              \
            int pp = (lane & 7) ^ (wrow & 7);                                      \
            const float* Wsrc = Wbase + (size_t)wrow * K + (st) * 32 + pp * 4;     \
            gload_lds(Wsrc, smem + 16384 + (sl) * 8192 + wv * 2048 + i * 1024);    \
        }                                                                          \
    }

    f32x4 acc[8];
    #pragma unroll
    for (int g = 0; g < 8; g++) acc[g] = (f32x4){0.f, 0.f, 0.f, 0.f};

    ISSUE(0, 0);                         // prologue: step 0 in flight

    int sw = (l15 & 7) << 4;             // read-side XOR (bytes, 16B-granular)
    for (int ks = 0; ks < nk; ks++) {
        int cur = ks & 1;
        if (ks + 1 < nk) {
            ISSUE(ks + 1, cur ^ 1);
            asm volatile("s_waitcnt vmcnt(4)" ::: "memory");   // own step-ks landed
        } else {
            asm volatile("s_waitcnt vmcnt(0)" ::: "memory");
        }
        __builtin_amdgcn_s_barrier();                          // all waves' step-ks in LDS
        asm volatile("" ::: "memory");

        const short* Acur = (const short*)(smem + cur * 8192);
        const char* Wrow = smem + 16384 + cur * 8192 + (wv * 16 + l15) * 128;
        f32x4 lo = *(const f32x4*)(Wrow + ((quad * 32) ^ sw));
        f32x4 hi = *(const f32x4*)(Wrow + ((quad * 32 + 16) ^ sw));
        union { unsigned u[4]; s16x8 v; } bu;
        bu.u[0] = pk2(lo[0], lo[1]); bu.u[1] = pk2(lo[2], lo[3]);
        bu.u[2] = pk2(hi[0], hi[1]); bu.u[3] = pk2(hi[2], hi[3]);
        s16x8 bw = bu.v;
        const short* Ap = Acur + quad * 1024 + l15 * 8;
        #pragma unroll
        for (int g = 0; g < 8; g++) {
            s16x8 af = *(const s16x8*)(Ap + g * 128);
            acc[g] = MFMA16(af, bw, acc[g]);
        }
        asm volatile("" ::: "memory");
        __builtin_amdgcn_s_barrier();    // slot fully consumed before next ISSUE
    }
#undef ISSUE

    size_t pb = (size_t)blockIdx.y * MM * N;
    int col = nb + wv * 16 + l15;
    #pragma unroll
    for (int g = 0; g < 8; g++)
        #pragma unroll
        for (int r = 0; r < 4; r++) {
            int row = g * 16 + quad * 4 + r;
            P[pb + (size_t)row * N + col] = acc[g][r];
        }
}

// ---------------- fused reduce_qkv + bias + RoPE ----------------
__global__ __launch_bounds__(128) void reduce_qkv_rope(const float* __restrict__ P,
                                                       const float* __restrict__ bq,
                                                       const float* __restrict__ bk,
                                                       const float* __restrict__ bv,
                                                       const int* __restrict__ offp,
                                                       float* __restrict__ C) {
    int row = blockIdx.y;                        // token row 0..127
    int u = blockIdx.x * 128 + threadIdx.x;      // 0..639
    int chunk = u >> 5, j = u & 31;              // 20 chunks of 128 feats
    int d0 = 2 * j;
    int c_lo = chunk * 128 + d0, c_hi = c_lo + 64;
    float2 slo = {0.f, 0.f}, shi = {0.f, 0.f};
    #pragma unroll
    for (int sx = 0; sx < 8; sx++) {
        const float* p = P + (size_t)sx * (MM * LDQKV) + (size_t)row * LDQKV;
        float2 a = *(const float2*)(p + c_lo);
        float2 b = *(const float2*)(p + c_hi);
        slo.x += a.x; slo.y += a.y; shi.x += b.x; shi.y += b.y;
    }
    const float* bptr; int cl;
    if (chunk < 16)      { bptr = bq; cl = c_lo; }
    else if (chunk < 18) { bptr = bk; cl = c_lo - 2048; }
    else                 { bptr = bv; cl = c_lo - 2304; }
    float2 blo = *(const float2*)(bptr + cl);
    float2 bhi = *(const float2*)(bptr + cl + 64);
    slo.x += blo.x; slo.y += blo.y; shi.x += bhi.x; shi.y += bhi.y;
    if (chunk < 18) {                            // rope on q and k only
        float pos = (float)(offp[0] + (row & 15));
        float inv0 = exp2f(-(float)(d0)     * (13.287712379549449f / 64.0f));
        float inv1 = exp2f(-(float)(d0 + 1) * (13.287712379549449f / 64.0f));
        float s0, c0, s1, c1;
        sincosf(pos * inv0, &s0, &c0);
        sincosf(pos * inv1, &s1, &c1);
        float2 olo, ohi;
        olo.x = slo.x * c0 - shi.x * s0; ohi.x = shi.x * c0 + slo.x * s0;
        olo.y = slo.y * c1 - shi.y * s1; ohi.y = shi.y * c1 + slo.y * s1;
        slo = olo; shi = ohi;
    }
    float* cp = C + (size_t)row * LDQKV;
    *(float2*)(cp + c_lo) = slo;
    *(float2*)(cp + c_hi) = shi;
}

// ---------------- fused reduce_res + RMSNorm -> hb + bf16 fragged ----------------
template<int SK>
__global__ __launch_bounds__(256) void reduce_res_rms(const float* __restrict__ P,
                                                      const float* __restrict__ res,
                                                      const float* __restrict__ w,
                                                      float* __restrict__ hb,
                                                      unsigned short* __restrict__ hnf) {
    int row = blockIdx.x, t = threadIdx.x;
    int e = t * 8;
    f32x4 s0 = *(const f32x4*)(res + (size_t)row * EE + e);
    f32x4 s1 = *(const f32x4*)(res + (size_t)row * EE + e + 4);
    #pragma unroll
    for (int sx = 0; sx < SK; sx++) {
        const float* p = P + (size_t)sx * (MM * EE) + (size_t)row * EE + e;
        s0 += *(const f32x4*)(p);
        s1 += *(const f32x4*)(p + 4);
    }
    *(f32x4*)(hb + (size_t)row * EE + e) = s0;
    *(f32x4*)(hb + (size_t)row * EE + e + 4) = s1;
    float ss = s0[0]*s0[0] + s0[1]*s0[1] + s0[2]*s0[2] + s0[3]*s0[3]
             + s1[0]*s1[0] + s1[1]*s1[1] + s1[2]*s1[2] + s1[3]*s1[3];
    #pragma unroll
    for (int o = 32; o > 0; o >>= 1) ss += __shfl_down(ss, o);
    __shared__ float red[4];
    if ((t & 63) == 0) red[t >> 6] = ss;
    __syncthreads();
    float tot = red[0] + red[1] + red[2] + red[3];
    float inv = rsqrtf(tot * (1.0f / (float)EE) + 1e-6f);
    f32x4 w0 = *(const f32x4*)(w + e), w1 = *(const f32x4*)(w + e + 4);
    f32x4 o0, o1;
    #pragma unroll
    for (int k = 0; k < 4; k++) { o0[k] = s0[k]*inv*w0[k]; o1[k] = s1[k]*inv*w1[k]; }
    unsigned short* dst = hnf + (t >> 2) * 4096 + (t & 3) * 1024 + row * 8;
    *(uint4*)dst = make_uint4(pk2(o0[0], o0[1]), pk2(o0[2], o0[3]),
                              pk2(o1[0], o1[1]), pk2(o1[2], o1[3]));
}

template<int SK>
__global__ __launch_bounds__(256) void reduce_res(const float* __restrict__ P,
                                                  const float* __restrict__ res,
                                                  float* __restrict__ C) {
    int e4 = (blockIdx.x * 256 + threadIdx.x) * 4;   // over 128*2048
    f32x4 s = *(const f32x4*)(res + e4);
    #pragma unroll
    for (int sx = 0; sx < SK; sx++)
        s += *(const f32x4*)(P + (size_t)sx * (MM * EE) + e4);
    *(f32x4*)(C + e4) = s;
}

// gate|up partials (SK=3) -> silu(g)*u -> bf16 fragged A (for down-proj, K=5632)
__global__ __launch_bounds__(256) void reduce_gateup(const float* __restrict__ P,
                                                     unsigned short* __restrict__ gbf) {
    int e4 = (blockIdx.x * 256 + threadIdx.x) * 4;   // over 128*5632
    int m = e4 / FF, f = e4 % FF;
    f32x4 g = {0.f,0.f,0.f,0.f}, u = g;
    #pragma unroll
    for (int sx = 0; sx < 3; sx++) {
        size_t base = (size_t)sx * (MM * 11264) + (size_t)m * 11264;
        g += *(const f32x4*)(P + base + f);
        u += *(const f32x4*)(P + base + 5632 + f);
    }
    f32x4 r;
    #pragma unroll
    for (int j = 0; j < 4; j++)
        r[j] = g[j] / (1.f + __expf(-g[j])) * u[j];
    unsigned short* dst = gbf + (f >> 5) * 4096 + ((f >> 3) & 3) * 1024 + m * 8 + (f & 7);
    *(uint2*)dst = make_uint2(pk2(r[0], r[1]), pk2(r[2], r[3]));
}

// ---------------- Flash-decode MFMA attention ----------------
// v3 (best measured): 1-D grid with XCD-pair swizzle — the two rh-halves of a
// (split,bkv) pair get block IDs 8 apart (same XCD under round-robin,
// temporally adjacent) so the second K/V read hits that XCD's L2. 1024 blocks,
// 4 blocks/CU, reg-prefetch K/V + double-buffered LDS, 1 sync/step.

#define LD_KV(S0_)                                                                       \
    {                                                                                    \
        int sK = (S0_) + keyk; if (sK > STOT - 1) sK = STOT - 1;                         \
        const float* kp = (sK < S0C)                                                     \
            ? ck + ((size_t)(b * 2 + kv) * S0C + sK) * 128 + dck * 16                    \
            : qkv + 2048 + (size_t)(b * 16 + (sK - S0C)) * LDQKV + kv * 128 + dck * 16;  \
        kr[0] = *(const float4*)(kp);                                                    \
        kr[1] = *(const float4*)(kp + 4);                                                \
        kr[2] = *(const float4*)(kp + 8);                                                \
        kr[3] = *(const float4*)(kp + 12);                                               \
        int sV = (S0_) + cV; if (sV > STOT - 1) sV = STOT - 1;                           \
        const float* vp = (sV < S0C)                                                     \
            ? cv + ((size_t)(b * 2 + kv) * S0C + sV) * 128 + dchV * 16                   \
            : qkv + 2304 + (size_t)(b * 16 + (sV - S0C)) * LDQKV + kv * 128 + dchV * 16; \
        vr[0] = *(const float4*)(vp);                                                    \
        vr[1] = *(const float4*)(vp + 4);                                                \
        vr[2] = *(const float4*)(vp + 8);                                                \
        vr[3] = *(const float4*)(vp + 12);                                               \
    }

__global__ __launch_bounds__(256, 4) void attn_kernel(const float* __restrict__ qkv,
                                                      const float* __restrict__ ck,
                                                      const float* __restrict__ cv,
                                                      const int* __restrict__ offp,
                                                      unsigned short* __restrict__ Os,
                                                      float* __restrict__ Mw,
                                                      float* __restrict__ Lw) {
    __shared__ __align__(16) char smem[39424];
    short* Qs = (short*)smem;
    short* Ps = (short*)(smem + 33792);
    float* mrow = (float*)(smem + 38912);
    float* lrow = (float*)(smem + 39168);

    int t = threadIdx.x;
    int wv = t >> 6, lane = t & 63, quad = lane >> 4, l15 = lane & 15;
    // XCD-pair decode: lin = 16m + 8*rh + j ; pair index p = 8m + j
    int lin = blockIdx.x;
    int j8 = lin & 7, rh = (lin >> 3) & 1, m = lin >> 4;
    int p = m * 8 + j8;                  // 0..511
    int split = p & 31;
    int bkv = p >> 5;
    int b = bkv >> 1, kv = bkv & 1;
    int off = offp[0];
    const float scl = 0.08838834764831845f;

    int s_begin = split * 128;
    int s_end = (split == NSPLIT - 1) ? STOT : s_begin + 128;
    int nst = (s_end - s_begin + 31) >> 5;

    int keyk = t >> 3, dck = t & 7;      // K: 32 keys x 8 d-chunks of 16 floats
    int cV = t & 31, dchV = t >> 5;      // V: 32 keys x 8 d-chunks of 16 floats
    float4 kr[4], vr[4];

    LD_KV(s_begin);

    {
        int row = t >> 2, qtr = t & 3;
        int g = rh * 64 + row;
        int l = g & 15, hg = g >> 4;
        const float* qp = qkv + (size_t)(b * 16 + l) * LDQKV + (kv * 8 + hg) * 128 + qtr * 32;
        unsigned* Qu = (unsigned*)(Qs + row * 136 + qtr * 32);
        #pragma unroll
        for (int i = 0; i < 4; i++) {
            float4 a  = *(const float4*)(qp + i * 8);
            float4 b4 = *(const float4*)(qp + i * 8 + 4);
            *(uint4*)(Qu + i * 4) = make_uint4(pk2(a.x*scl, a.y*scl), pk2(a.z*scl, a.w*scl),
                                               pk2(b4.x*scl, b4.y*scl), pk2(b4.z*scl, b4.w*scl));
        }
    }
    if (t < 64) { mrow[t] = -1e30f; lrow[t] = 0.f; }
    __syncthreads();

    s16x8 qf[4];
    #pragma unroll
    for (int ks = 0; ks < 4; ks++)
        qf[ks] = *(const s16x8*)(Qs + (wv * 16 + l15) * 136 + ks * 32 + quad * 8);

    f32x4 oacc[8];
    #pragma unroll
    for (int nt = 0; nt < 8; nt++)
        oacc[nt] = (f32x4){0.f, 0.f, 0.f, 0.f};

    __syncthreads();   // all qf reads done before Ks[0] (overlapping Qs) is written

    for (int i = 0; i < nst; i++) {
        int s0 = s_begin + i * 32;
        int cs = min(32, s_end - s0);
        int pp = i & 1;
        short* Ksp = (short*)(smem + pp * 8704);
        short* Vtp = (short*)(smem + 17408 + pp * 8192);

        {
            unsigned* Ku = (unsigned*)(Ksp + keyk * 136 + dck * 16);
            *(uint4*)Ku     = make_uint4(pk2(kr[0].x, kr[0].y), pk2(kr[0].z, kr[0].w),
                                         pk2(kr[1].x, kr[1].y), pk2(kr[1].z, kr[1].w));
            *(uint4*)(Ku+4) = make_uint4(pk2(kr[2].x, kr[2].y), pk2(kr[2].z, kr[2].w),
                                         pk2(kr[3].x, kr[3].y), pk2(kr[3].z, kr[3].w));
            const float* vv = (const float*)vr;
            #pragma unroll
            for (int jj = 0; jj < 16; jj++) {
                int vrow = dchV * 16 + jj;
                Vtp[(vrow << 5) + (cV ^ (((vrow >> 1) & 3) << 3))] = (short)f2bfu(vv[jj]);
            }
        }
        __syncthreads();

        if (i + 1 < nst) LD_KV(s0 + 32);

        f32x4 sa[2];
        sa[0] = (f32x4){0.f,0.f,0.f,0.f};
        sa[1] = sa[0];
        #pragma unroll
        for (int ks = 0; ks < 4; ks++) {
            #pragma unroll
            for (int nt = 0; nt < 2; nt++) {
                s16x8 kf = *(const s16x8*)(Ksp + (nt * 16 + l15) * 136 + ks * 32 + quad * 8);
                sa[nt] = MFMA16(qf[ks], kf, sa[nt]);
            }
        }

        float alpha[4];
        #pragma unroll
        for (int r = 0; r < 4; r++) {
            int row = wv * 16 + quad * 4 + r;
            int ltok = row & 15;
            float s0v = sa[0][r];
            float s1v = sa[1][r];
            int g0 = s0 + l15, g1 = s0 + 16 + l15;
            bool ok0 = (l15 < cs) && (g0 <= off + ltok);
            bool ok1 = (16 + l15 < cs) && (g1 <= off + ltok);
            s0v = ok0 ? s0v : -3e38f;
            s1v = ok1 ? s1v : -3e38f;
            float mc = fmaxf(s0v, s1v);
            mc = fmaxf(mc, __shfl_xor(mc, 1));
            mc = fmaxf(mc, __shfl_xor(mc, 2));
            mc = fmaxf(mc, __shfl_xor(mc, 4));
            mc = fmaxf(mc, __shfl_xor(mc, 8));
            float mold = mrow[row];
            float mnew = fmaxf(mold, mc);
            float al = __expf(mold - mnew);
            float p0 = __expf(s0v - mnew);
            float p1 = __expf(s1v - mnew);
            float rs = p0 + p1;
            rs += __shfl_xor(rs, 1);
            rs += __shfl_xor(rs, 2);
            rs += __shfl_xor(rs, 4);
            rs += __shfl_xor(rs, 8);
            if (l15 == 0) { mrow[row] = mnew; lrow[row] = lrow[row] * al + rs; }
            alpha[r] = al;
            Ps[row * 40 + l15] = (short)f2bfu(p0);
            Ps[row * 40 + 16 + l15] = (short)f2bfu(p1);
        }
        #pragma unroll
        for (int nt = 0; nt < 8; nt++)
            #pragma unroll
            for (int r = 0; r < 4; r++)
                oacc[nt][r] *= alpha[r];

        s16x8 pf = *(const s16x8*)(Ps + (wv * 16 + l15) * 40 + quad * 8);
        #pragma unroll
        for (int nt = 0; nt < 8; nt++) {
            int vrow = nt * 16 + l15;
            s16x8 vf = *(const s16x8*)(Vtp + (vrow << 5) + ((quad ^ ((vrow >> 1) & 3)) << 3));
            oacc[nt] = MFMA16(pf, vf, oacc[nt]);
        }
    }

    __syncthreads();
    size_t obase = (size_t)(split * 16 + bkv) * 128;
    int rbase = rh * 64;
    #pragma unroll
    for (int nt = 0; nt < 8; nt++)
        #pragma unroll
        for (int r = 0; r < 4; r++) {
            int row = wv * 16 + quad * 4 + r;
            Os[(obase + rbase + row) * 128 + nt * 16 + l15] = f2bfu(oacc[nt][r]);
        }
    if (t < 64) { Mw[obase + rbase + t] = mrow[t]; Lw[obase + rbase + t] = lrow[t]; }
}

// ---------------- merge split partials -> bf16 fragged A (for o-proj, K=2048) ------
__global__ __launch_bounds__(256) void merge_kernel(const unsigned short* __restrict__ Os,
                                                    const float* __restrict__ Mw,
                                                    const float* __restrict__ Lw,
                                                    unsigned short* __restrict__ obf) {
    int blk = blockIdx.x;
    int bkv = blk >> 3, rg = blk & 7;
    int b = bkv >> 1, kv = bkv & 1;
    int t = threadIdx.x;
    int rowl = t >> 4;
    int row = rg * 16 + rowl;
    int dchunk = (t & 15) * 8;
    float M = -3e38f;
    for (int s = 0; s < NSPLIT; s++)
        M = fmaxf(M, Mw[((size_t)s * 16 + bkv) * 128 + row]);
    float denom = 0.f;
    float o[8];
    #pragma unroll
    for (int j = 0; j < 8; j++) o[j] = 0.f;
    for (int s = 0; s < NSPLIT; s++) {
        size_t base = ((size_t)s * 16 + bkv) * 128 + row;
        float w = __expf(Mw[base] - M);
        denom += Lw[base] * w;
        uint4 u = *(const uint4*)(Os + base * 128 + dchunk);
        o[0] += w * bf2f((unsigned short)(u.x & 0xffff));
        o[1] += w * bf2f((unsigned short)(u.x >> 16));
        o[2] += w * bf2f((unsigned short)(u.y & 0xffff));
        o[3] += w * bf2f((unsigned short)(u.y >> 16));
        o[4] += w * bf2f((unsigned short)(u.z & 0xffff));
        o[5] += w * bf2f((unsigned short)(u.z >> 16));
        o[6] += w * bf2f((unsigned short)(u.w & 0xffff));
        o[7] += w * bf2f((unsigned short)(u.w >> 16));
    }
    float inv = 1.f / denom;
    #pragma unroll
    for (int j = 0; j < 8; j++) o[j] *= inv;
    int m = b * 16 + rowl;                         // token row for o-proj A
    int e0 = (kv * 8 + rg) * 128 + dchunk;         // feature col, 8-aligned
    unsigned short* dst = obf + (e0 >> 5) * 4096 + ((e0 >> 3) & 3) * 1024 + m * 8;
    *(uint4*)dst = make_uint4(pk2(o[0], o[1]), pk2(o[2], o[3]),
                              pk2(o[4], o[5]), pk2(o[6], o[7]));
}

// ---------------- launch ----------------
extern "C" void kernel_launch(void* const* d_in, const int* in_sizes, int n_in,
                              void* d_out, int out_size, void* d_ws, size_t ws_size,
                              hipStream_t stream) {
    const float* x        = (const float*)d_in[0];
    const float* cache_k  = (const float*)d_in[1];
    const float* cache_v  = (const float*)d_in[2];
    const float* wq       = (const float*)d_in[3];
    const float* wk       = (const float*)d_in[4];
    const float* wv       = (const float*)d_in[5];
    const float* wo       = (const float*)d_in[6];
    const float* bq       = (const float*)d_in[7];
    const float* bk       = (const float*)d_in[8];
    const float* bv       = (const float*)d_in[9];
    const float* w_gate   = (const float*)d_in[10];
    const float* w_up     = (const float*)d_in[11];
    const float* w_down   = (const float*)d_in[12];
    const float* w_in_ln  = (const float*)d_in[13];
    const float* w_post_ln= (const float*)d_in[14];
    const int*   offp     = (const int*)d_in[15];
    float* out = (float*)d_out;

    float* ws = (float*)d_ws;
    float* qkvb = ws;                                   // 327680
    float* hb   = ws + 327680;                          // 262144 -> 589824
    unsigned short* xnf = (unsigned short*)(ws + 589824);   // 128*2048 bf16 = 131072 f
    unsigned short* hnf = (unsigned short*)(ws + 720896);   // 131072 f
    unsigned short* obf = (unsigned short*)(ws + 851968);   // 131072 f
    unsigned short* gbf = (unsigned short*)(ws + 983040);   // 128*5632 bf16 = 360448 f
    float* R = ws + 1343488;                            // P (<=4325376 f) / Os+Mw+Lw (4325376 f)
    float* P = R;
    unsigned short* Osw = (unsigned short*)R;
    float* Mw = R + 4194304;
    float* Lw = R + 4259840;                            // end: 5668864 f = 22.7 MB

    const int BIG = 1 << 30;

    // 1) input RMSNorm -> bf16 fragged
    rmsnorm_bf16<<<MM, 256, 0, stream>>>(x, w_in_ln, xnf);
    // 2) QKV: N=2560, K=2048, SK=8 (Kc=256, nk=8) -> 320 blocks
    gemm_cs<<<dim3(40, 8), 256, 0, stream>>>(xnf, wq, wk, wv, 2048, 2304, 2048, 256, P, LDQKV);
    // 3) fused bias + reduce + RoPE
    reduce_qkv_rope<<<dim3(5, 128), 128, 0, stream>>>(P, bq, bk, bv, offp, qkvb);
    // 4) attention, XCD-pair swizzled 1-D grid (1024 blocks, 4/CU)
    attn_kernel<<<dim3(1024), 256, 0, stream>>>(qkvb, cache_k, cache_v, offp, Osw, Mw, Lw);
    merge_kernel<<<128, 256, 0, stream>>>(Osw, Mw, Lw, obf);
    // 5) O-proj: N=2048, K=2048, SK=16 (Kc=128, nk=4) -> 512 blocks; P=4.19Mf
    gemm_cs<<<dim3(32, 16), 256, 0, stream>>>(obf, wo, wo, wo, BIG, BIG, 2048, 128, P, EE);
    // 6) fused residual reduce + post RMSNorm -> hb + bf16 fragged hnf
    reduce_res_rms<16><<<MM, 256, 0, stream>>>(P, x, w_post_ln, hb, hnf);
    // 7) Gate|Up: N=11264, K=2048, SK=3 (Kc=704; y=2 gets 640) -> 528 blocks; P=4.33Mf
    gemm_cs<<<dim3(176, 3), 256, 0, stream>>>(hnf, w_gate, w_up, w_up, 5632, BIG, 2048, 704, P, 11264);
    reduce_gateup<<<704, 256, 0, stream>>>(P, gbf);
    // 8) Down: N=2048, K=5632, SK=15 (Kc=384; y=14 gets 256) -> 480 blocks; P=3.93Mf
    gemm_cs<<<dim3(32, 15), 256, 0, stream>>>(gbf, w_down, w_down, w_down, BIG, BIG, 5632, 384, P, EE);
    reduce_res<15><<<256, 256, 0, stream>>>(P, hb, out);
}

// Round 12
// 323.524 us; speedup vs baseline: 1.0066x; 1.0066x over previous
//
#include <hip/hip_runtime.h>
#include <math.h>

// Qwen2 block: B=8 L=16 E=2048 S0=4096 F=5632 H=16 HKV=2 D=128
#define MM 128
#define EE 2048
#define FF 5632
#define S0C 4096
#define STOT 4112
#define NSPLIT 32
#define LDQKV 2560

typedef float f32x4 __attribute__((ext_vector_type(4)));
typedef short s16x8 __attribute__((ext_vector_type(8)));

#define MFMA16(a, b, c) __builtin_amdgcn_mfma_f32_16x16x32_bf16(a, b, c, 0, 0, 0)

// round-half-up fp32->bf16 (1 VALU); pack two via v_perm (3 VALU / 2 elems)
__device__ __forceinline__ unsigned short f2bfu(float f) {
    return (unsigned short)((__float_as_uint(f) + 0x8000u) >> 16);
}
__device__ __forceinline__ unsigned pk2(float lo, float hi) {
    return __builtin_amdgcn_perm(__float_as_uint(hi) + 0x8000u,
                                 __float_as_uint(lo) + 0x8000u, 0x07060302u);
}
__device__ __forceinline__ float bf2f(unsigned short u) {
    return __uint_as_float(((unsigned)u) << 16);
}

// async global->LDS DMA: 16B/lane, dest = wave-uniform base + lane*16
__device__ __forceinline__ void gload_lds(const void* g, void* l) {
    __builtin_amdgcn_global_load_lds(
        (const __attribute__((address_space(1))) void*)g,
        (__attribute__((address_space(3))) void*)l, 16, 0, 0);
}

// A-fragment layout: element (row, k) of A[128][K] lives at
//   (k>>5)*4096 + ((k>>3)&3)*1024 + row*8 + (k&7)    (shorts)
// so each 64-k step is one contiguous 16KB block; frag reads from it are dense.

// ---------------- RMSNorm -> bf16 fragged A ----------------
__global__ __launch_bounds__(256) void rmsnorm_bf16(const float* __restrict__ x,
                                                    const float* __restrict__ w,
                                                    unsigned short* __restrict__ out) {
    int row = blockIdx.x;
    int t = threadIdx.x;
    const float4* xr = (const float4*)(x + row * EE);
    float4 a = xr[2 * t];
    float4 b = xr[2 * t + 1];
    float ss = a.x*a.x + a.y*a.y + a.z*a.z + a.w*a.w
             + b.x*b.x + b.y*b.y + b.z*b.z + b.w*b.w;
    #pragma unroll
    for (int o = 32; o > 0; o >>= 1) ss += __shfl_down(ss, o);
    __shared__ float red[4];
    if ((t & 63) == 0) red[t >> 6] = ss;
    __syncthreads();
    float tot = red[0] + red[1] + red[2] + red[3];
    float inv = rsqrtf(tot * (1.0f / (float)EE) + 1e-6f);
    const float4* wr = (const float4*)w;
    float4 w0 = wr[2 * t], w1 = wr[2 * t + 1];
    float4 o0, o1;
    o0.x = a.x*inv*w0.x; o0.y = a.y*inv*w0.y; o0.z = a.z*inv*w0.z; o0.w = a.w*inv*w0.w;
    o1.x = b.x*inv*w1.x; o1.y = b.y*inv*w1.y; o1.z = b.z*inv*w1.z; o1.w = b.w*inv*w1.w;
    unsigned short* dst = out + (t >> 2) * 4096 + (t & 3) * 1024 + row * 8;
    *(uint4*)dst = make_uint4(pk2(o0.x, o0.y), pk2(o0.z, o0.w),
                              pk2(o1.x, o1.y), pk2(o1.z, o1.w));
}

// ---------------- streaming GEMM v8 (best measured): 64k T3/T4 ring ----------------
// Block = 128 rows x 64 cols, 256 threads (4 waves x 128r x 16c).
// Depth-2 LDS ring, per 64-k step: A 16KB bf16 (linear DMA) + W 16KB fp32
// (DMA with source-pre-swizzled 16B units; 256B-granular W row runs).
// Counted vmcnt, never 0 mid-loop. Kc % 64 == 0; last y-split may be short.
// P[sk][128][N] fp32 partials.
__global__ __launch_bounds__(256) void gemm_cs(const unsigned short* __restrict__ Af,
                                               const float* __restrict__ W0,
                                               const float* __restrict__ W1,
                                               const float* __restrict__ W2,
                                               int cut1, int cut2,
                                               int K, int Kc,
                                               float* __restrict__ P, int N) {
    __shared__ __align__(16) char smem[65536];   // A: 2x16KB @0, W: 2x16KB @32768
    int t = threadIdx.x;
    int wv = t >> 6, lane = t & 63, quad = lane >> 4, l15 = lane & 15;
    int nb = blockIdx.x * 64;
    const float* Wm; int nn;
    if (nb < cut1)      { Wm = W0; nn = nb; }
    else if (nb < cut2) { Wm = W1; nn = nb - cut1; }
    else                { Wm = W2; nn = nb - cut2; }
    int kbeg = blockIdx.y * Kc;
    const float* Wbase = Wm + (size_t)nn * K + kbeg;
    const unsigned short* Ab = Af + (kbeg >> 5) * 4096;
    int nk = min(Kc, K - kbeg) >> 6;

#define ISSUE(st, sl)                                                              \
    {                                                                              \
        const char* Asrc = (const char*)Ab + (size_t)(st) * 16384 + wv * 4096      \
                           + lane * 16;                                            \
        char* Adst = smem + (sl) * 16384 + wv * 4096;                              \
        _Pragma("unroll")                                                          \
        for (int i = 0; i < 4; i++)                                                \
            gload_lds(Asrc + i * 1024, Adst + i * 1024);                           \
        _Pragma("unroll")                                                          \
        for (int i = 0; i < 4; i++) {                                              \
            int wrow = wv * 16 + i * 4 + (lane >> 4);                              \
            int pp = (lane & 15) ^ (wrow & 7);                                     \
            const float* Wsrc = Wbase + (size_t)wrow * K + (st) * 64 + pp * 4;     \
            gload_lds(Wsrc, smem + 32768 + (sl) * 16384 + wv * 4096 + i * 1024);   \
        }                                                                          \
    }

    f32x4 acc[8];
    #pragma unroll
    for (int g = 0; g < 8; g++) acc[g] = (f32x4){0.f, 0.f, 0.f, 0.f};

    ISSUE(0, 0);                         // prologue: step 0 in flight

    int sw = (l15 & 7) << 4;             // read-side XOR (bytes, 16B-granular)
    for (int ks = 0; ks < nk; ks++) {
        int cur = ks & 1;
        if (ks + 1 < nk) {
            ISSUE(ks + 1, cur ^ 1);
            asm volatile("s_waitcnt vmcnt(8)" ::: "memory");   // own step-ks landed
        } else {
            asm volatile("s_waitcnt vmcnt(0)" ::: "memory");
        }
        __builtin_amdgcn_s_barrier();                          // all waves' step-ks in LDS
        asm volatile("" ::: "memory");

        const short* Acur = (const short*)(smem + cur * 16384);
        const char* Wrow = smem + 32768 + cur * 16384 + (wv * 16 + l15) * 256;
        #pragma unroll
        for (int s = 0; s < 2; s++) {
            int base = s * 128 + quad * 32;
            f32x4 lo = *(const f32x4*)(Wrow + (base ^ sw));
            f32x4 hi = *(const f32x4*)(Wrow + ((base + 16) ^ sw));
            union { unsigned u[4]; s16x8 v; } bu;
            bu.u[0] = pk2(lo[0], lo[1]); bu.u[1] = pk2(lo[2], lo[3]);
            bu.u[2] = pk2(hi[0], hi[1]); bu.u[3] = pk2(hi[2], hi[3]);
            s16x8 bw = bu.v;
            const short* Ap = Acur + s * 4096 + quad * 1024 + l15 * 8;
            #pragma unroll
            for (int g = 0; g < 8; g++) {
                s16x8 af = *(const s16x8*)(Ap + g * 128);
                acc[g] = MFMA16(af, bw, acc[g]);
            }
        }
        asm volatile("" ::: "memory");
        __builtin_amdgcn_s_barrier();    // slot fully consumed before next ISSUE
    }
#undef ISSUE

    size_t pb = (size_t)blockIdx.y * MM * N;
    int col = nb + wv * 16 + l15;
    #pragma unroll
    for (int g = 0; g < 8; g++)
        #pragma unroll
        for (int r = 0; r < 4; r++) {
            int row = g * 16 + quad * 4 + r;
            P[pb + (size_t)row * N + col] = acc[g][r];
        }
}

// ---------------- fused reduce_qkv + bias + RoPE ----------------
__global__ __launch_bounds__(128) void reduce_qkv_rope(const float* __restrict__ P,
                                                       const float* __restrict__ bq,
                                                       const float* __restrict__ bk,
                                                       const float* __restrict__ bv,
                                                       const int* __restrict__ offp,
                                                       float* __restrict__ C) {
    int row = blockIdx.y;                        // token row 0..127
    int u = blockIdx.x * 128 + threadIdx.x;      // 0..639
    int chunk = u >> 5, j = u & 31;              // 20 chunks of 128 feats
    int d0 = 2 * j;
    int c_lo = chunk * 128 + d0, c_hi = c_lo + 64;
    float2 slo = {0.f, 0.f}, shi = {0.f, 0.f};
    #pragma unroll
    for (int sx = 0; sx < 8; sx++) {
        const float* p = P + (size_t)sx * (MM * LDQKV) + (size_t)row * LDQKV;
        float2 a = *(const float2*)(p + c_lo);
        float2 b = *(const float2*)(p + c_hi);
        slo.x += a.x; slo.y += a.y; shi.x += b.x; shi.y += b.y;
    }
    const float* bptr; int cl;
    if (chunk < 16)      { bptr = bq; cl = c_lo; }
    else if (chunk < 18) { bptr = bk; cl = c_lo - 2048; }
    else                 { bptr = bv; cl = c_lo - 2304; }
    float2 blo = *(const float2*)(bptr + cl);
    float2 bhi = *(const float2*)(bptr + cl + 64);
    slo.x += blo.x; slo.y += blo.y; shi.x += bhi.x; shi.y += bhi.y;
    if (chunk < 18) {                            // rope on q and k only
        float pos = (float)(offp[0] + (row & 15));
        float inv0 = exp2f(-(float)(d0)     * (13.287712379549449f / 64.0f));
        float inv1 = exp2f(-(float)(d0 + 1) * (13.287712379549449f / 64.0f));
        float s0, c0, s1, c1;
        sincosf(pos * inv0, &s0, &c0);
        sincosf(pos * inv1, &s1, &c1);
        float2 olo, ohi;
        olo.x = slo.x * c0 - shi.x * s0; ohi.x = shi.x * c0 + slo.x * s0;
        olo.y = slo.y * c1 - shi.y * s1; ohi.y = shi.y * c1 + slo.y * s1;
        slo = olo; shi = ohi;
    }
    float* cp = C + (size_t)row * LDQKV;
    *(float2*)(cp + c_lo) = slo;
    *(float2*)(cp + c_hi) = shi;
}

// ---------------- fused reduce_res + RMSNorm -> hb + bf16 fragged ----------------
template<int SK>
__global__ __launch_bounds__(256) void reduce_res_rms(const float* __restrict__ P,
                                                      const float* __restrict__ res,
                                                      const float* __restrict__ w,
                                                      float* __restrict__ hb,
                                                      unsigned short* __restrict__ hnf) {
    int row = blockIdx.x, t = threadIdx.x;
    int e = t * 8;
    f32x4 s0 = *(const f32x4*)(res + (size_t)row * EE + e);
    f32x4 s1 = *(const f32x4*)(res + (size_t)row * EE + e + 4);
    #pragma unroll
    for (int sx = 0; sx < SK; sx++) {
        const float* p = P + (size_t)sx * (MM * EE) + (size_t)row * EE + e;
        s0 += *(const f32x4*)(p);
        s1 += *(const f32x4*)(p + 4);
    }
    *(f32x4*)(hb + (size_t)row * EE + e) = s0;
    *(f32x4*)(hb + (size_t)row * EE + e + 4) = s1;
    float ss = s0[0]*s0[0] + s0[1]*s0[1] + s0[2]*s0[2] + s0[3]*s0[3]
             + s1[0]*s1[0] + s1[1]*s1[1] + s1[2]*s1[2] + s1[3]*s1[3];
    #pragma unroll
    for (int o = 32; o > 0; o >>= 1) ss += __shfl_down(ss, o);
    __shared__ float red[4];
    if ((t & 63) == 0) red[t >> 6] = ss;
    __syncthreads();
    float tot = red[0] + red[1] + red[2] + red[3];
    float inv = rsqrtf(tot * (1.0f / (float)EE) + 1e-6f);
    f32x4 w0 = *(const f32x4*)(w + e), w1 = *(const f32x4*)(w + e + 4);
    f32x4 o0, o1;
    #pragma unroll
    for (int k = 0; k < 4; k++) { o0[k] = s0[k]*inv*w0[k]; o1[k] = s1[k]*inv*w1[k]; }
    unsigned short* dst = hnf + (t >> 2) * 4096 + (t & 3) * 1024 + row * 8;
    *(uint4*)dst = make_uint4(pk2(o0[0], o0[1]), pk2(o0[2], o0[3]),
                              pk2(o1[0], o1[1]), pk2(o1[2], o1[3]));
}

template<int SK>
__global__ __launch_bounds__(256) void reduce_res(const float* __restrict__ P,
                                                  const float* __restrict__ res,
                                                  float* __restrict__ C) {
    int e4 = (blockIdx.x * 256 + threadIdx.x) * 4;   // over 128*2048
    f32x4 s = *(const f32x4*)(res + e4);
    #pragma unroll
    for (int sx = 0; sx < SK; sx++)
        s += *(const f32x4*)(P + (size_t)sx * (MM * EE) + e4);
    *(f32x4*)(C + e4) = s;
}

// gate|up partials (SK=3) -> silu(g)*u -> bf16 fragged A (for down-proj, K=5632)
__global__ __launch_bounds__(256) void reduce_gateup(const float* __restrict__ P,
                                                     unsigned short* __restrict__ gbf) {
    int e4 = (blockIdx.x * 256 + threadIdx.x) * 4;   // over 128*5632
    int m = e4 / FF, f = e4 % FF;
    f32x4 g = {0.f,0.f,0.f,0.f}, u = g;
    #pragma unroll
    for (int sx = 0; sx < 3; sx++) {
        size_t base = (size_t)sx * (MM * 11264) + (size_t)m * 11264;
        g += *(const f32x4*)(P + base + f);
        u += *(const f32x4*)(P + base + 5632 + f);
    }
    f32x4 r;
    #pragma unroll
    for (int j = 0; j < 4; j++)
        r[j] = g[j] / (1.f + __expf(-g[j])) * u[j];
    unsigned short* dst = gbf + (f >> 5) * 4096 + ((f >> 3) & 3) * 1024 + m * 8 + (f & 7);
    *(uint2*)dst = make_uint2(pk2(r[0], r[1]), pk2(r[2], r[3]));
}

// ---------------- Flash-decode MFMA attention ----------------
// v3 (best measured): 1-D grid with XCD-pair swizzle — the two rh-halves of a
// (split,bkv) pair get block IDs 8 apart (same XCD under round-robin,
// temporally adjacent) so the second K/V read hits that XCD's L2. 1024 blocks,
// 4 blocks/CU, reg-prefetch K/V + double-buffered LDS, 1 sync/step.

#define LD_KV(S0_)                                                                       \
    {                                                                                    \
        int sK = (S0_) + keyk; if (sK > STOT - 1) sK = STOT - 1;                         \
        const float* kp = (sK < S0C)                                                     \
            ? ck + ((size_t)(b * 2 + kv) * S0C + sK) * 128 + dck * 16                    \
            : qkv + 2048 + (size_t)(b * 16 + (sK - S0C)) * LDQKV + kv * 128 + dck * 16;  \
        kr[0] = *(const float4*)(kp);                                                    \
        kr[1] = *(const float4*)(kp + 4);                                                \
        kr[2] = *(const float4*)(kp + 8);                                                \
        kr[3] = *(const float4*)(kp + 12);                                               \
        int sV = (S0_) + cV; if (sV > STOT - 1) sV = STOT - 1;                           \
        const float* vp = (sV < S0C)                                                     \
            ? cv + ((size_t)(b * 2 + kv) * S0C + sV) * 128 + dchV * 16                   \
            : qkv + 2304 + (size_t)(b * 16 + (sV - S0C)) * LDQKV + kv * 128 + dchV * 16; \
        vr[0] = *(const float4*)(vp);                                                    \
        vr[1] = *(const float4*)(vp + 4);                                                \
        vr[2] = *(const float4*)(vp + 8);                                                \
        vr[3] = *(const float4*)(vp + 12);                                               \
    }

__global__ __launch_bounds__(256, 4) void attn_kernel(const float* __restrict__ qkv,
                                                      const float* __restrict__ ck,
                                                      const float* __restrict__ cv,
                                                      const int* __restrict__ offp,
                                                      unsigned short* __restrict__ Os,
                                                      float* __restrict__ Mw,
                                                      float* __restrict__ Lw) {
    __shared__ __align__(16) char smem[39424];
    short* Qs = (short*)smem;
    short* Ps = (short*)(smem + 33792);
    float* mrow = (float*)(smem + 38912);
    float* lrow = (float*)(smem + 39168);

    int t = threadIdx.x;
    int wv = t >> 6, lane = t & 63, quad = lane >> 4, l15 = lane & 15;
    // XCD-pair decode: lin = 16m + 8*rh + j ; pair index p = 8m + j
    int lin = blockIdx.x;
    int j8 = lin & 7, rh = (lin >> 3) & 1, m = lin >> 4;
    int p = m * 8 + j8;                  // 0..511
    int split = p & 31;
    int bkv = p >> 5;
    int b = bkv >> 1, kv = bkv & 1;
    int off = offp[0];
    const float scl = 0.08838834764831845f;

    int s_begin = split * 128;
    int s_end = (split == NSPLIT - 1) ? STOT : s_begin + 128;
    int nst = (s_end - s_begin + 31) >> 5;

    int keyk = t >> 3, dck = t & 7;      // K: 32 keys x 8 d-chunks of 16 floats
    int cV = t & 31, dchV = t >> 5;      // V: 32 keys x 8 d-chunks of 16 floats
    float4 kr[4], vr[4];

    LD_KV(s_begin);

    {
        int row = t >> 2, qtr = t & 3;
        int g = rh * 64 + row;
        int l = g & 15, hg = g >> 4;
        const float* qp = qkv + (size_t)(b * 16 + l) * LDQKV + (kv * 8 + hg) * 128 + qtr * 32;
        unsigned* Qu = (unsigned*)(Qs + row * 136 + qtr * 32);
        #pragma unroll
        for (int i = 0; i < 4; i++) {
            float4 a  = *(const float4*)(qp + i * 8);
            float4 b4 = *(const float4*)(qp + i * 8 + 4);
            *(uint4*)(Qu + i * 4) = make_uint4(pk2(a.x*scl, a.y*scl), pk2(a.z*scl, a.w*scl),
                                               pk2(b4.x*scl, b4.y*scl), pk2(b4.z*scl, b4.w*scl));
        }
    }
    if (t < 64) { mrow[t] = -1e30f; lrow[t] = 0.f; }
    __syncthreads();

    s16x8 qf[4];
    #pragma unroll
    for (int ks = 0; ks < 4; ks++)
        qf[ks] = *(const s16x8*)(Qs + (wv * 16 + l15) * 136 + ks * 32 + quad * 8);

    f32x4 oacc[8];
    #pragma unroll
    for (int nt = 0; nt < 8; nt++)
        oacc[nt] = (f32x4){0.f, 0.f, 0.f, 0.f};

    __syncthreads();   // all qf reads done before Ks[0] (overlapping Qs) is written

    for (int i = 0; i < nst; i++) {
        int s0 = s_begin + i * 32;
        int cs = min(32, s_end - s0);
        int pp = i & 1;
        short* Ksp = (short*)(smem + pp * 8704);
        short* Vtp = (short*)(smem + 17408 + pp * 8192);

        {
            unsigned* Ku = (unsigned*)(Ksp + keyk * 136 + dck * 16);
            *(uint4*)Ku     = make_uint4(pk2(kr[0].x, kr[0].y), pk2(kr[0].z, kr[0].w),
                                         pk2(kr[1].x, kr[1].y), pk2(kr[1].z, kr[1].w));
            *(uint4*)(Ku+4) = make_uint4(pk2(kr[2].x, kr[2].y), pk2(kr[2].z, kr[2].w),
                                         pk2(kr[3].x, kr[3].y), pk2(kr[3].z, kr[3].w));
            const float* vv = (const float*)vr;
            #pragma unroll
            for (int jj = 0; jj < 16; jj++) {
                int vrow = dchV * 16 + jj;
                Vtp[(vrow << 5) + (cV ^ (((vrow >> 1) & 3) << 3))] = (short)f2bfu(vv[jj]);
            }
        }
        __syncthreads();

        if (i + 1 < nst) LD_KV(s0 + 32);

        f32x4 sa[2];
        sa[0] = (f32x4){0.f,0.f,0.f,0.f};
        sa[1] = sa[0];
        #pragma unroll
        for (int ks = 0; ks < 4; ks++) {
            #pragma unroll
            for (int nt = 0; nt < 2; nt++) {
                s16x8 kf = *(const s16x8*)(Ksp + (nt * 16 + l15) * 136 + ks * 32 + quad * 8);
                sa[nt] = MFMA16(qf[ks], kf, sa[nt]);
            }
        }

        float alpha[4];
        #pragma unroll
        for (int r = 0; r < 4; r++) {
            int row = wv * 16 + quad * 4 + r;
            int ltok = row & 15;
            float s0v = sa[0][r];
            float s1v = sa[1][r];
            int g0 = s0 + l15, g1 = s0 + 16 + l15;
            bool ok0 = (l15 < cs) && (g0 <= off + ltok);
            bool ok1 = (16 + l15 < cs) && (g1 <= off + ltok);
            s0v = ok0 ? s0v : -3e38f;
            s1v = ok1 ? s1v : -3e38f;
            float mc = fmaxf(s0v, s1v);
            mc = fmaxf(mc, __shfl_xor(mc, 1));
            mc = fmaxf(mc, __shfl_xor(mc, 2));
            mc = fmaxf(mc, __shfl_xor(mc, 4));
            mc = fmaxf(mc, __shfl_xor(mc, 8));
            float mold = mrow[row];
            float mnew = fmaxf(mold, mc);
            float al = __expf(mold - mnew);
            float p0 = __expf(s0v - mnew);
            float p1 = __expf(s1v - mnew);
            float rs = p0 + p1;
            rs += __shfl_xor(rs, 1);
            rs += __shfl_xor(rs, 2);
            rs += __shfl_xor(rs, 4);
            rs += __shfl_xor(rs, 8);
            if (l15 == 0) { mrow[row] = mnew; lrow[row] = lrow[row] * al + rs; }
            alpha[r] = al;
            Ps[row * 40 + l15] = (short)f2bfu(p0);
            Ps[row * 40 + 16 + l15] = (short)f2bfu(p1);
        }
        #pragma unroll
        for (int nt = 0; nt < 8; nt++)
            #pragma unroll
            for (int r = 0; r < 4; r++)
                oacc[nt][r] *= alpha[r];

        s16x8 pf = *(const s16x8*)(Ps + (wv * 16 + l15) * 40 + quad * 8);
        #pragma unroll
        for (int nt = 0; nt < 8; nt++) {
            int vrow = nt * 16 + l15;
            s16x8 vf = *(const s16x8*)(Vtp + (vrow << 5) + ((quad ^ ((vrow >> 1) & 3)) << 3));
            oacc[nt] = MFMA16(pf, vf, oacc[nt]);
        }
    }

    __syncthreads();
    size_t obase = (size_t)(split * 16 + bkv) * 128;
    int rbase = rh * 64;
    #pragma unroll
    for (int nt = 0; nt < 8; nt++)
        #pragma unroll
        for (int r = 0; r < 4; r++) {
            int row = wv * 16 + quad * 4 + r;
            Os[(obase + rbase + row) * 128 + nt * 16 + l15] = f2bfu(oacc[nt][r]);
        }
    if (t < 64) { Mw[obase + rbase + t] = mrow[t]; Lw[obase + rbase + t] = lrow[t]; }
}

// ---------------- merge split partials -> bf16 fragged A (for o-proj, K=2048) ------
__global__ __launch_bounds__(256) void merge_kernel(const unsigned short* __restrict__ Os,
                                                    const float* __restrict__ Mw,
                                                    const float* __restrict__ Lw,
                                                    unsigned short* __restrict__ obf) {
    int blk = blockIdx.x;
    int bkv = blk >> 3, rg = blk & 7;
    int b = bkv >> 1, kv = bkv & 1;
    int t = threadIdx.x;
    int rowl = t >> 4;
    int row = rg * 16 + rowl;
    int dchunk = (t & 15) * 8;
    float M = -3e38f;
    for (int s = 0; s < NSPLIT; s++)
        M = fmaxf(M, Mw[((size_t)s * 16 + bkv) * 128 + row]);
    float denom = 0.f;
    float o[8];
    #pragma unroll
    for (int j = 0; j < 8; j++) o[j] = 0.f;
    for (int s = 0; s < NSPLIT; s++) {
        size_t base = ((size_t)s * 16 + bkv) * 128 + row;
        float w = __expf(Mw[base] - M);
        denom += Lw[base] * w;
        uint4 u = *(const uint4*)(Os + base * 128 + dchunk);
        o[0] += w * bf2f((unsigned short)(u.x & 0xffff));
        o[1] += w * bf2f((unsigned short)(u.x >> 16));
        o[2] += w * bf2f((unsigned short)(u.y & 0xffff));
        o[3] += w * bf2f((unsigned short)(u.y >> 16));
        o[4] += w * bf2f((unsigned short)(u.z & 0xffff));
        o[5] += w * bf2f((unsigned short)(u.z >> 16));
        o[6] += w * bf2f((unsigned short)(u.w & 0xffff));
        o[7] += w * bf2f((unsigned short)(u.w >> 16));
    }
    float inv = 1.f / denom;
    #pragma unroll
    for (int j = 0; j < 8; j++) o[j] *= inv;
    int m = b * 16 + rowl;                         // token row for o-proj A
    int e0 = (kv * 8 + rg) * 128 + dchunk;         // feature col, 8-aligned
    unsigned short* dst = obf + (e0 >> 5) * 4096 + ((e0 >> 3) & 3) * 1024 + m * 8;
    *(uint4*)dst = make_uint4(pk2(o[0], o[1]), pk2(o[2], o[3]),
                              pk2(o[4], o[5]), pk2(o[6], o[7]));
}

// ---------------- launch ----------------
extern "C" void kernel_launch(void* const* d_in, const int* in_sizes, int n_in,
                              void* d_out, int out_size, void* d_ws, size_t ws_size,
                              hipStream_t stream) {
    const float* x        = (const float*)d_in[0];
    const float* cache_k  = (const float*)d_in[1];
    const float* cache_v  = (const float*)d_in[2];
    const float* wq       = (const float*)d_in[3];
    const float* wk       = (const float*)d_in[4];
    const float* wv       = (const float*)d_in[5];
    const float* wo       = (const float*)d_in[6];
    const float* bq       = (const float*)d_in[7];
    const float* bk       = (const float*)d_in[8];
    const float* bv       = (const float*)d_in[9];
    const float* w_gate   = (const float*)d_in[10];
    const float* w_up     = (const float*)d_in[11];
    const float* w_down   = (const float*)d_in[12];
    const float* w_in_ln  = (const float*)d_in[13];
    const float* w_post_ln= (const float*)d_in[14];
    const int*   offp     = (const int*)d_in[15];
    float* out = (float*)d_out;

    float* ws = (float*)d_ws;
    float* qkvb = ws;                                   // 327680
    float* hb   = ws + 327680;                          // 262144 -> 589824
    unsigned short* xnf = (unsigned short*)(ws + 589824);   // 128*2048 bf16 = 131072 f
    unsigned short* hnf = (unsigned short*)(ws + 720896);   // 131072 f
    unsigned short* obf = (unsigned short*)(ws + 851968);   // 131072 f
    unsigned short* gbf = (unsigned short*)(ws + 983040);   // 128*5632 bf16 = 360448 f
    float* R = ws + 1343488;                            // P (<=4325376 f) / Os+Mw+Lw (4325376 f)
    float* P = R;
    unsigned short* Osw = (unsigned short*)R;
    float* Mw = R + 4194304;
    float* Lw = R + 4259840;                            // end: 5668864 f = 22.7 MB

    const int BIG = 1 << 30;

    // 1) input RMSNorm -> bf16 fragged
    rmsnorm_bf16<<<MM, 256, 0, stream>>>(x, w_in_ln, xnf);
    // 2) QKV: N=2560, K=2048, SK=8 (Kc=256, nk=4) -> 320 blocks
    gemm_cs<<<dim3(40, 8), 256, 0, stream>>>(xnf, wq, wk, wv, 2048, 2304, 2048, 256, P, LDQKV);
    // 3) fused bias + reduce + RoPE
    reduce_qkv_rope<<<dim3(5, 128), 128, 0, stream>>>(P, bq, bk, bv, offp, qkvb);
    // 4) attention, XCD-pair swizzled 1-D grid (1024 blocks, 4/CU)
    attn_kernel<<<dim3(1024), 256, 0, stream>>>(qkvb, cache_k, cache_v, offp, Osw, Mw, Lw);
    merge_kernel<<<128, 256, 0, stream>>>(Osw, Mw, Lw, obf);
    // 5) O-proj: N=2048, K=2048, SK=16 (Kc=128, nk=2) -> 512 blocks; P=4.19Mf
    gemm_cs<<<dim3(32, 16), 256, 0, stream>>>(obf, wo, wo, wo, BIG, BIG, 2048, 128, P, EE);
    // 6) fused residual reduce + post RMSNorm -> hb + bf16 fragged hnf
    reduce_res_rms<16><<<MM, 256, 0, stream>>>(P, x, w_post_ln, hb, hnf);
    // 7) Gate|Up: N=11264, K=2048, SK=3 (Kc=704; y=2 gets 640) -> 528 blocks; P=4.33Mf
    gemm_cs<<<dim3(176, 3), 256, 0, stream>>>(hnf, w_gate, w_up, w_up, 5632, BIG, 2048, 704, P, 11264);
    reduce_gateup<<<704, 256, 0, stream>>>(P, gbf);
    // 8) Down: N=2048, K=5632, SK=15 (Kc=384; y=14 gets 256) -> 480 blocks; P=3.93Mf
    gemm_cs<<<dim3(32, 15), 256, 0, stream>>>(gbf, w_down, w_down, w_down, BIG, BIG, 5632, 384, P, EE);
    reduce_res<15><<<256, 256, 0, stream>>>(P, hb, out);
}